// Round 1
// baseline (423.283 us; speedup 1.0000x reference)
//
#include <hip/hip_runtime.h>
#include <stdint.h>

typedef __attribute__((ext_vector_type(8))) short bhalf8;
typedef __attribute__((ext_vector_type(8))) unsigned short u16x8;
typedef __attribute__((ext_vector_type(4))) float f32x4;

static constexpr int kLayers = 16;
static constexpr int kBN = 64;
static constexpr int kSteps = 8;  // K=512 in steps of BK=64

__device__ __forceinline__ unsigned short f2bf(float f) {
  unsigned int u = __float_as_uint(f);
  u += 0x7FFFu + ((u >> 16) & 1u);   // RNE
  return (unsigned short)(u >> 16);
}

__device__ __forceinline__ void gload_lds16(const void* g, void* l) {
  __builtin_amdgcn_global_load_lds(
      (const __attribute__((address_space(1))) void*)g,
      (__attribute__((address_space(3))) void*)l, 16, 0, 0);
}

// W (16,256,256,2) fp32 -> bf16, per-layer K-step tiles [m=256][k'=64],
// byte-in-tile = m*128 + ((2k') ^ ((m&7)<<4))  (element: k' ^ ((m&7)<<3))
__global__ void convert_w_kernel(const float* __restrict__ W,
                                 unsigned short* __restrict__ wbf) {
  int tid = blockIdx.x * 256 + threadIdx.x;  // 0..2097151
  int k = tid & 511;                         // k = 2*cin + tap
  int c = (tid >> 9) & 255;                  // cout
  int base = tid & ~0x1FFFF;                 // layer*131072
  int ks = k >> 6;
  int kk = k & 63;
  int dst = base + ks * 16384 + c * 64 + (kk ^ ((c & 7) << 3));
  wbf[dst] = f2bf(W[tid]);
}

// One layer: out[c][n] = tanh(bias[c] + sum_k A[c][k]*B[k][n]),
// A = W[i] (256x512, pre-swizzled bf16), B[k=2c'+tap][n] = in[c'][2(n0+n)+tap]
__global__ __launch_bounds__(256, 2)
void wavenet_layer(const float* __restrict__ x0,
                   const unsigned short* __restrict__ actin,
                   unsigned short* __restrict__ actout,
                   float* __restrict__ fout,
                   const unsigned short* __restrict__ wl,
                   const float* __restrict__ bias,
                   int N, int Tin, int isL0, int isFinal) {
  __shared__ __align__(16) unsigned char lds[40960];
  // [0,32768): A tile [m=256][k'=64] bf16 (swizzled). [32768,40960): B [n=64][k''=64]
  const int tid = threadIdx.x;
  const int lane = tid & 63;
  const int w = tid >> 6;
  const int l15 = lane & 15;
  const int l4 = lane >> 4;
  const long n0 = (long)blockIdx.x * kBN;

  f32x4 acc[4][4];
#pragma unroll
  for (int a = 0; a < 4; ++a)
#pragma unroll
    for (int bq = 0; bq < 4; ++bq) acc[a][bq] = (f32x4)0.0f;

  for (int ks = 0; ks < kSteps; ++ks) {
    // ---- stage A: 32 KB linear copy (layout pre-swizzled in global)
    {
      const unsigned short* src = wl + ks * 16384;
#pragma unroll
      for (int r = 0; r < 8; ++r) {
        gload_lds16(src + r * 2048 + tid * 8,
                    (void*)(lds + r * 4096 + w * 1024));
      }
    }
    // ---- stage B: 64 k x 64 n bf16 (swizzled rows of 128 B)
    if (isL0) {
#pragma unroll
      for (int p = 0; p < 4; ++p) {
        int idx = p * 256 + tid;     // 1024 float4 loads
        int cpp = idx >> 5;          // c'' 0..31
        int fch = idx & 31;          // 4-float chunk along t
        long t = 2 * n0 + 4 * fch;
        const float* row = x0 + ((long)(32 * ks + cpp) << 16);
        f32x4 v = *(const f32x4*)(row + t);
        unsigned int lo = (unsigned)f2bf(v[0]) | ((unsigned)f2bf(v[1]) << 16);
        unsigned int hi = (unsigned)f2bf(v[2]) | ((unsigned)f2bf(v[3]) << 16);
        int colb = 4 * cpp;
        int nl = 2 * fch;
        *(unsigned int*)(lds + 32768 + nl * 128 + (colb ^ ((nl & 7) << 4))) = lo;
        nl++;
        *(unsigned int*)(lds + 32768 + nl * 128 + (colb ^ ((nl & 7) << 4))) = hi;
      }
    } else {
#pragma unroll
      for (int p = 0; p < 2; ++p) {
        int idx = p * 256 + tid;     // 512 16B loads
        int cpp = idx >> 4;          // c'' 0..31
        int ch = idx & 15;           // 8-elem chunk along t
        long t = 2 * n0 + 8 * ch;
        const unsigned short* row = actin + (long)(32 * ks + cpp) * Tin;
        u16x8 v;
        if (t + 8 <= Tin) {
          v = *(const u16x8*)(row + t);
        } else {
#pragma unroll
          for (int e = 0; e < 8; ++e)
            v[e] = (t + e < (long)Tin) ? row[t + e] : (unsigned short)0;
        }
        int colb = 4 * cpp;
#pragma unroll
        for (int d = 0; d < 4; ++d) {
          int nl = 4 * ch + d;
          unsigned int pk = (unsigned)v[2 * d] | ((unsigned)v[2 * d + 1] << 16);
          *(unsigned int*)(lds + 32768 + nl * 128 + (colb ^ ((nl & 7) << 4))) = pk;
        }
      }
    }
    __syncthreads();
    // ---- MFMA: wave w owns rows [64w,64w+64), 4x4 tiles of 16x16
#pragma unroll
    for (int k2 = 0; k2 < 2; ++k2) {
      bhalf8 af[4], bfv[4];
      int colbase = k2 * 64 + 16 * l4;
#pragma unroll
      for (int mt = 0; mt < 4; ++mt) {
        int m = 64 * w + 16 * mt + l15;
        af[mt] = *(const bhalf8*)(lds + m * 128 + (colbase ^ ((m & 7) << 4)));
      }
#pragma unroll
      for (int nt = 0; nt < 4; ++nt) {
        int n = 16 * nt + l15;
        bfv[nt] = *(const bhalf8*)(lds + 32768 + n * 128 + (colbase ^ ((n & 7) << 4)));
      }
#pragma unroll
      for (int mt = 0; mt < 4; ++mt)
#pragma unroll
        for (int nt = 0; nt < 4; ++nt)
          acc[mt][nt] = __builtin_amdgcn_mfma_f32_16x16x32_bf16(
              af[mt], bfv[nt], acc[mt][nt], 0, 0, 0);
    }
    __syncthreads();
  }

  if (isFinal) {  // N==1: store fp32 result for n==0 only
    if (l15 == 0) {
#pragma unroll
      for (int mt = 0; mt < 4; ++mt)
#pragma unroll
        for (int r = 0; r < 4; ++r) {
          int c = 64 * w + 16 * mt + 4 * l4 + r;
          fout[c] = tanhf(acc[mt][0][r] + bias[c]);
        }
    }
    return;
  }

  // ---- epilogue: bias+tanh, transpose through LDS (reuse A region), store bf16
#pragma unroll
  for (int mt = 0; mt < 4; ++mt) {
    int cbase = 64 * w + 16 * mt + 4 * l4;
#pragma unroll
    for (int r = 0; r < 4; ++r) {
      int c = cbase + r;
      float bs = bias[c];
#pragma unroll
      for (int nt = 0; nt < 4; ++nt) {
        int n = 16 * nt + l15;
        *(unsigned short*)(lds + c * 128 + ((2 * n) ^ ((c & 7) << 4))) =
            f2bf(tanhf(acc[mt][nt][r] + bs));
      }
    }
  }
  __syncthreads();
#pragma unroll
  for (int p = 0; p < 8; ++p) {
    int idx = p * 256 + tid;
    int c = idx >> 3;
    int ch = idx & 7;
    u16x8 v = *(const u16x8*)(lds + c * 128 + ((16 * ch) ^ ((c & 7) << 4)));
    long ng = n0 + 8 * ch;
    if (ng + 8 <= (long)N) {
      *(u16x8*)(actout + (long)c * N + ng) = v;
    } else if (ng < (long)N) {
#pragma unroll
      for (int e = 0; e < 8; ++e)
        if (ng + e < (long)N) actout[(long)c * N + ng + e] = v[e];
    }
  }
}

extern "C" void kernel_launch(void* const* d_in, const int* in_sizes, int n_in,
                              void* d_out, int out_size, void* d_ws, size_t ws_size,
                              hipStream_t stream) {
  (void)in_sizes; (void)n_in; (void)out_size; (void)ws_size;
  const float* x = (const float*)d_in[0];
  const float* W = (const float*)d_in[1];
  const float* b = (const float*)d_in[2];
  float* out = (float*)d_out;
  unsigned short* wbf = (unsigned short*)d_ws;                       // 4 MB
  unsigned short* actA = (unsigned short*)((char*)d_ws + (4l << 20));  // 16 MB
  unsigned short* actB = (unsigned short*)((char*)d_ws + (20l << 20)); // 8 MB

  convert_w_kernel<<<dim3(8192), dim3(256), 0, stream>>>(W, wbf);

  int N = 32768;
  for (int i = 0; i < kLayers; ++i) {
    int Tin = N * 2;
    const unsigned short* ain = (i == 0) ? nullptr : ((i & 1) ? actA : actB);
    unsigned short* aout = (i & 1) ? actB : actA;
    int isFinal = (i == kLayers - 1) ? 1 : 0;
    int grid = (N + kBN - 1) / kBN;
    wavenet_layer<<<dim3(grid), dim3(256), 0, stream>>>(
        (i == 0) ? x : nullptr, ain, isFinal ? nullptr : aout,
        isFinal ? out : nullptr, wbf + i * 131072, b + i * 256, N, Tin,
        (i == 0) ? 1 : 0, isFinal);
    N >>= 1;
  }
}

// Round 2
// 220.223 us; speedup vs baseline: 1.9221x; 1.9221x over previous
//
#include <hip/hip_runtime.h>
#include <stdint.h>

typedef __attribute__((ext_vector_type(8))) short bhalf8;
typedef __attribute__((ext_vector_type(8))) unsigned short u16x8;
typedef __attribute__((ext_vector_type(4))) float f32x4;

__device__ __forceinline__ unsigned short f2bf(float f) {
  unsigned int u = __float_as_uint(f);
  u += 0x7FFFu + ((u >> 16) & 1u);  // RNE
  return (unsigned short)(u >> 16);
}

__device__ __forceinline__ void gload16(const void* g, void* l) {
  __builtin_amdgcn_global_load_lds(
      (const __attribute__((address_space(1))) void*)g,
      (__attribute__((address_space(3))) void*)l, 16, 0, 0);
}

// W (16,256,256,2) fp32 -> bf16 A-tiles: per layer, per kstep [m=256][k'=64],
// element-in-tile = m*64 + (k' ^ ((m&7)<<3))
__global__ void convert_w_kernel(const float* __restrict__ W,
                                 unsigned short* __restrict__ wbf) {
  int tid = blockIdx.x * 256 + threadIdx.x;
  int k = tid & 511;
  int c = (tid >> 9) & 255;
  int base = tid & ~0x1FFFF;
  int ks = k >> 6;
  int kk = k & 63;
  wbf[base + ks * 16384 + c * 64 + (kk ^ ((c & 7) << 3))] = f2bf(W[tid]);
}

// Layer 0: A = W0 (256x512), B[k=2c'+t][n] = x[c'][2n+t]. Out -> act0 in
// B-layout: row r = n>>1 (1KB of 512 bf16, swizzled), k = 2c + (n&1).
__global__ __launch_bounds__(256, 4)
void layer0_kernel(const float* __restrict__ x0,
                   unsigned short* __restrict__ act0,
                   const unsigned short* __restrict__ w0,
                   const float* __restrict__ bias0) {
  __shared__ __align__(16) unsigned char lds[40960];
  const int tid = threadIdx.x;
  const int lane = tid & 63, w = tid >> 6, l15 = lane & 15, l4 = lane >> 4;
  const long n0 = (long)blockIdx.x * 64;

  f32x4 acc[4][4];
#pragma unroll
  for (int a = 0; a < 4; ++a)
#pragma unroll
    for (int bq = 0; bq < 4; ++bq) acc[a][bq] = (f32x4)0.0f;

  for (int ks = 0; ks < 8; ++ks) {
    const unsigned short* src = w0 + ks * 16384;
#pragma unroll
    for (int rr = 0; rr < 8; ++rr)
      gload16(src + rr * 2048 + tid * 8, lds + rr * 4096 + w * 1024);
#pragma unroll
    for (int p = 0; p < 4; ++p) {
      int idx = p * 256 + tid;
      int cpp = idx >> 5;
      int fch = idx & 31;
      long t = 2 * n0 + 4 * fch;
      const float* row = x0 + ((long)(32 * ks + cpp) << 16);
      f32x4 v = *(const f32x4*)(row + t);
      unsigned int lo = (unsigned)f2bf(v[0]) | ((unsigned)f2bf(v[1]) << 16);
      unsigned int hi = (unsigned)f2bf(v[2]) | ((unsigned)f2bf(v[3]) << 16);
      int colb = 4 * cpp;
      int nl = 2 * fch;
      *(unsigned int*)(lds + 32768 + nl * 128 + (colb ^ ((nl & 7) << 4))) = lo;
      nl++;
      *(unsigned int*)(lds + 32768 + nl * 128 + (colb ^ ((nl & 7) << 4))) = hi;
    }
    __syncthreads();
#pragma unroll
    for (int k2 = 0; k2 < 2; ++k2) {
      int colbase = k2 * 64 + 16 * l4;
      bhalf8 af[4], bfv[4];
#pragma unroll
      for (int mt = 0; mt < 4; ++mt) {
        int m = 64 * w + 16 * mt + l15;
        af[mt] = *(const bhalf8*)(lds + m * 128 + (colbase ^ ((m & 7) << 4)));
      }
#pragma unroll
      for (int nt = 0; nt < 4; ++nt) {
        int n = 16 * nt + l15;
        bfv[nt] = *(const bhalf8*)(lds + 32768 + n * 128 + (colbase ^ ((n & 7) << 4)));
      }
#pragma unroll
      for (int mt = 0; mt < 4; ++mt)
#pragma unroll
        for (int nt = 0; nt < 4; ++nt)
          acc[mt][nt] = __builtin_amdgcn_mfma_f32_16x16x32_bf16(
              af[mt], bfv[nt], acc[mt][nt], 0, 0, 0);
    }
    __syncthreads();
  }
  // epilogue: B-layout staging (reuse A region), then linear copy
#pragma unroll
  for (int mt = 0; mt < 4; ++mt) {
    int cb_ = 64 * w + 16 * mt + 4 * l4;
#pragma unroll
    for (int q = 0; q < 4; ++q) {
      int c = cb_ + q;
      float bs = bias0[c];
#pragma unroll
      for (int nt = 0; nt < 4; ++nt) {
        int n = 16 * nt + l15;
        unsigned short v = f2bf(tanhf(acc[mt][nt][q] + bs));
        int r2 = n >> 1;
        *(unsigned short*)(lds + r2 * 1024 +
                           ((4 * c + 2 * (n & 1)) ^ ((r2 & 7) << 4))) = v;
      }
    }
  }
  __syncthreads();
#pragma unroll
  for (int p = 0; p < 8; ++p)
    *(u16x8*)(act0 + (long)blockIdx.x * 16384 + p * 2048 + tid * 8) =
        *(const u16x8*)(lds + p * 4096 + tid * 16);
}

// Fused tree kernel: NL layers, block-local (no halo). Input: ROWS_IN rows of
// B-layout act. A-tiles double-buffered, counted vmcnt(8) + raw barriers.
template <int NL, int ROWS_IN, int BN_OUT, int FINAL>
__global__ __launch_bounds__(256, 1)
void tree_kernel(const unsigned short* __restrict__ actin,
                 unsigned short* __restrict__ actout,
                 float* __restrict__ fout,
                 const unsigned short* __restrict__ wbase,
                 const float* __restrict__ biasbase) {
  constexpr int BIN = ROWS_IN * 1024;
  constexpr int AOFF = BIN;
  constexpr int BOFF = BIN + 65536;
  __shared__ __align__(16) unsigned char lds[BIN + 65536 + NL * 1024];
  const int tid = threadIdx.x;
  const int lane = tid & 63, w = tid >> 6, l15 = lane & 15, l4 = lane >> 4;
  const long blk = blockIdx.x;

  // prologue: stage Bin, bias, A(0)
  {
    const unsigned short* src = actin + blk * (ROWS_IN * 512);
#pragma unroll
    for (int rr = 0; rr < BIN / 4096; ++rr)
      gload16(src + rr * 2048 + w * 512 + lane * 8, lds + rr * 4096 + w * 1024);
#pragma unroll
    for (int cb = 0; cb < NL; ++cb)
      if (w == (cb & 3))
        gload16(biasbase + cb * 256 + lane * 4, lds + BOFF + cb * 1024);
#pragma unroll
    for (int rr = 0; rr < 8; ++rr)
      gload16(wbase + rr * 2048 + w * 512 + lane * 8,
              lds + AOFF + rr * 4096 + w * 1024);
  }

  f32x4 acc[4][4];
#pragma unroll
  for (int a = 0; a < 4; ++a)
#pragma unroll
    for (int bq = 0; bq < 4; ++bq) acc[a][bq] = (f32x4)0.0f;

  constexpr int R = NL * 8;
  int r = 0;
#pragma unroll
  for (int j = 0; j < NL; ++j) {
    const int cols = ROWS_IN >> j;
    const int NT = (cols >= 64) ? 4 : (cols >= 32) ? 2 : 1;
    const int in_off = (j & 1) * (BIN / 2);
    const int out_off = (j & 1) ? 0 : (BIN / 2);
#pragma unroll
    for (int ks = 0; ks < 8; ++ks, ++r) {
      const int rn = r + 1;
      if (rn < R) {  // prefetch next A tile into other buffer
        const unsigned short* aw = wbase + (rn >> 3) * 131072 + (rn & 7) * 16384;
        unsigned char* ad = lds + AOFF + (rn & 1) * 32768;
#pragma unroll
        for (int rr2 = 0; rr2 < 8; ++rr2)
          gload16(aw + rr2 * 2048 + w * 512 + lane * 8,
                  ad + rr2 * 4096 + w * 1024);
        asm volatile("s_waitcnt vmcnt(8)" ::: "memory");
      } else {
        asm volatile("s_waitcnt vmcnt(0)" ::: "memory");
      }
      __builtin_amdgcn_sched_barrier(0);
      __builtin_amdgcn_s_barrier();
      const unsigned char* Ab = lds + AOFF + (r & 1) * 32768;
#pragma unroll
      for (int k2 = 0; k2 < 2; ++k2) {
        const int acol = k2 * 64 + 16 * l4;
        bhalf8 af[4], bfv[4];
#pragma unroll
        for (int mt = 0; mt < 4; ++mt) {
          int m = 64 * w + 16 * mt + l15;
          af[mt] = *(const bhalf8*)(Ab + m * 128 + (acol ^ ((m & 7) << 4)));
        }
        const int bcol = ks * 128 + acol;
#pragma unroll
        for (int nt = 0; nt < 4; ++nt)
          if (nt < NT) {
            int n = 16 * nt + l15;
            bfv[nt] = *(const bhalf8*)(lds + in_off + n * 1024 +
                                       (bcol ^ ((n & 7) << 4)));
          }
#pragma unroll
        for (int mt = 0; mt < 4; ++mt)
#pragma unroll
          for (int nt = 0; nt < 4; ++nt)
            if (nt < NT)
              acc[mt][nt] = __builtin_amdgcn_mfma_f32_16x16x32_bf16(
                  af[mt], bfv[nt], acc[mt][nt], 0, 0, 0);
      }
      if (ks == 7) {  // layer end
        __builtin_amdgcn_s_barrier();  // all reads of in-region complete
        if (FINAL && j == NL - 1) {
          if (l15 == 0) {
#pragma unroll
            for (int mt = 0; mt < 4; ++mt)
#pragma unroll
              for (int q = 0; q < 4; ++q) {
                int c = 64 * w + 16 * mt + 4 * l4 + q;
                float bs = *(const float*)(lds + BOFF + j * 1024 + c * 4);
                fout[c] = tanhf(acc[mt][0][q] + bs);
              }
          }
        } else if (j == NL - 1 && BN_OUT == 1) {
          long Rg = blk >> 1;
          int par = (int)(blk & 1);
          if (l15 == 0) {
#pragma unroll
            for (int mt = 0; mt < 4; ++mt)
#pragma unroll
              for (int q = 0; q < 4; ++q) {
                int c = 64 * w + 16 * mt + 4 * l4 + q;
                float bs = *(const float*)(lds + BOFF + j * 1024 + c * 4);
                unsigned short v = f2bf(tanhf(acc[mt][0][q] + bs));
                *(unsigned short*)((unsigned char*)actout + Rg * 1024 +
                                   ((4 * c + 2 * par) ^
                                    ((((int)Rg) & 7) << 4))) = v;
              }
          }
        } else {  // write next-layer B-layout into LDS
#pragma unroll
          for (int mt = 0; mt < 4; ++mt) {
            int cb_ = 64 * w + 16 * mt + 4 * l4;
#pragma unroll
            for (int q = 0; q < 4; ++q) {
              int c = cb_ + q;
              float bs = *(const float*)(lds + BOFF + j * 1024 + c * 4);
#pragma unroll
              for (int nt = 0; nt < 4; ++nt)
                if (nt < NT) {
                  int n = 16 * nt + l15;
                  if (n < cols) {
                    unsigned short v = f2bf(tanhf(acc[mt][nt][q] + bs));
                    int r2 = n >> 1;
                    *(unsigned short*)(lds + out_off + r2 * 1024 +
                                       ((4 * c + 2 * (n & 1)) ^
                                        ((r2 & 7) << 4))) = v;
                  }
                }
            }
          }
          asm volatile("s_waitcnt lgkmcnt(0)" ::: "memory");
        }
#pragma unroll
        for (int a = 0; a < 4; ++a)
#pragma unroll
          for (int bq = 0; bq < 4; ++bq) acc[a][bq] = (f32x4)0.0f;
      }
      __builtin_amdgcn_s_barrier();
    }
  }
  if (!FINAL && BN_OUT >= 2) {  // copy staged output tile to global
    constexpr int OUTB = (BN_OUT / 2) * 1024;
    const int src_off = ((NL - 1) & 1) ? 0 : (BIN / 2);
    unsigned short* dst = actout + blk * (BN_OUT / 2) * 512;
#pragma unroll
    for (int p = 0; p < OUTB / 4096; ++p)
      *(u16x8*)(dst + p * 2048 + tid * 8) =
          *(const u16x8*)(lds + src_off + p * 4096 + tid * 16);
  }
}

extern "C" void kernel_launch(void* const* d_in, const int* in_sizes, int n_in,
                              void* d_out, int out_size, void* d_ws, size_t ws_size,
                              hipStream_t stream) {
  (void)in_sizes; (void)n_in; (void)out_size; (void)ws_size;
  const float* x = (const float*)d_in[0];
  const float* W = (const float*)d_in[1];
  const float* b = (const float*)d_in[2];
  float* out = (float*)d_out;
  unsigned short* wbf = (unsigned short*)d_ws;                              // 4 MB
  unsigned short* act0 = (unsigned short*)((char*)d_ws + (4l << 20));       // 16 MB
  unsigned short* act2 = (unsigned short*)((char*)d_ws + (20l << 20));      // 4 MB
  unsigned short* act7 = (unsigned short*)((char*)d_ws + (24l << 20));      // 128 KB
  unsigned short* act12 = (unsigned short*)((char*)d_ws + (24l << 20) + (128l << 10));

  convert_w_kernel<<<dim3(8192), dim3(256), 0, stream>>>(W, wbf);
  layer0_kernel<<<dim3(512), dim3(256), 0, stream>>>(x, act0, wbf, b);
  tree_kernel<2, 64, 32, 0><<<dim3(256), dim3(256), 0, stream>>>(
      act0, act2, nullptr, wbf + 1 * 131072, b + 1 * 256);
  tree_kernel<5, 16, 1, 0><<<dim3(256), dim3(256), 0, stream>>>(
      act2, act7, nullptr, wbf + 3 * 131072, b + 3 * 256);
  tree_kernel<5, 16, 1, 0><<<dim3(8), dim3(256), 0, stream>>>(
      act7, act12, nullptr, wbf + 8 * 131072, b + 8 * 256);
  tree_kernel<3, 4, 1, 1><<<dim3(1), dim3(256), 0, stream>>>(
      act12, nullptr, out, wbf + 13 * 131072, b + 13 * 256);
}